// Round 9
// baseline (14317.722 us; speedup 1.0000x reference)
//
#include <hip/hip_runtime.h>

#define VOCABN 401
#define EN 256
#define HN 768
#define H3N 2304
#define ON 3
#define BN 64
#define TN 1024

// 16 replicas x 16 WGs; each WG: 48 j's, k split 8 ways, 4 batches
#define NREP 16
#define WGPR 16
#define BPR  4
#define JPW  48
#define NTH  384

typedef _Float16 f16x2 __attribute__((ext_vector_type(2)));
typedef _Float16 f16x8 __attribute__((ext_vector_type(8)));
union F16x8 { f16x8 v; f16x2 p[4]; };

__device__ __forceinline__ float fdot2(f16x2 a, f16x2 b, float c) {
#if __has_builtin(__builtin_amdgcn_fdot2)
    return __builtin_amdgcn_fdot2(a, b, c, false);
#else
    return c + (float)a[0] * (float)b[0] + (float)a[1] * (float)b[1];
#endif
}

// sum over each aligned 8-lane group; pure VALU via DPP (no DS pipe):
// quad_perm xor1, quad_perm xor2, row_half_mirror.
__device__ __forceinline__ float octet_sum(float x) {
    int v = __builtin_bit_cast(int, x);
    x += __builtin_bit_cast(float, __builtin_amdgcn_update_dpp(0, v, 0xB1, 0xF, 0xF, true));
    v = __builtin_bit_cast(int, x);
    x += __builtin_bit_cast(float, __builtin_amdgcn_update_dpp(0, v, 0x4E, 0xF, 0xF, true));
    v = __builtin_bit_cast(int, x);
    x += __builtin_bit_cast(float, __builtin_amdgcn_update_dpp(0, v, 0x141, 0xF, 0xF, true));
    return x;
}

// ---------------- K1: gtab[v][g] = dot(embed[v], W_ih[g]) + b_ih[g]  (w-stationary)
__global__ __launch_bounds__(256)
void k_build_gtab(const float* __restrict__ embed, const float* __restrict__ wih,
                  const float* __restrict__ bih, float* __restrict__ gtab) {
    const int g  = blockIdx.x * 64 + (threadIdx.x >> 2);
    const int ql = threadIdx.x & 3;
    const int v0 = blockIdx.y * 26;
    const int v1 = min(VOCABN, v0 + 26);
    float4 w[16];
    const float4* s4 = (const float4*)(wih + (size_t)g * EN + ql * 64);
#pragma unroll
    for (int i = 0; i < 16; ++i) w[i] = s4[i];
    const float bias = bih[g];
    for (int v = v0; v < v1; ++v) {
        const float4* e4 = (const float4*)(embed + (size_t)v * EN + ql * 64);
        float acc = 0.f;
#pragma unroll
        for (int i = 0; i < 16; ++i) {
            float4 e = e4[i];
            acc += w[i].x * e.x + w[i].y * e.y + w[i].z * e.z + w[i].w * e.w;
        }
        acc += __shfl_xor(acc, 1, 64);
        acc += __shfl_xor(acc, 2, 64);
        if (ql == 0) gtab[(size_t)v * H3N + g] = acc + bias;
    }
}

// ---------------- K2: persistent-weight recurrence; tag-in-data, batched self-poll.
// Each u32 h word: [31:16]=step tag, [15:0]=f16 h bits. The discovering load IS the
// data load: each thread polls its OWN 4 u64 words, all 4 issued in parallel per
// round (one waitcnt drain per round), s_sleep only on failure. No gate/flag/ack.
// Anti-overwrite safety: WG X stores tag t+2 only after consuming all tag-(t+1)
// words, which requires every WG to have stored t+1, which (program order) requires
// every WG to have consumed its tag-t words -> buf[t&1] is dead before overwrite.
// memset-0 == valid t=0 state (tag 0, h=0). Agent-scope relaxed atomics only.
__global__ __launch_bounds__(NTH, 1)
void k_rnn(const int* __restrict__ tokens, const float* __restrict__ whh,
           const float* __restrict__ gtab, const float* __restrict__ bhh,
           unsigned* __restrict__ hbuf, float* __restrict__ hout) {
    const int R   = blockIdx.x & (NREP - 1);
    const int wg  = blockIdx.x >> 4;
    const int tid = threadIdx.x;
    const int jl  = tid >> 3;
    const int q   = tid & 7;
    const int j   = wg * JPW + jl;

    __shared__ __align__(16) _Float16 hlds[32 * 112];   // [b*8+qslot][96 data + 16 pad]

    // ---- one-time: weight slice -> 36 statically-indexed f16x8 (rows j,768+j,1536+j; k-octile q)
    F16x8 w[3][12];
#pragma unroll
    for (int g = 0; g < 3; ++g) {
        const float4* s4 = (const float4*)(whh + (size_t)(g * HN + j) * HN + q * 96);
#pragma unroll
        for (int c = 0; c < 12; ++c) {
            float4 a = s4[2 * c], b4 = s4[2 * c + 1];
            F16x8 t;
            t.v[0] = (_Float16)a.x;  t.v[1] = (_Float16)a.y;
            t.v[2] = (_Float16)a.z;  t.v[3] = (_Float16)a.w;
            t.v[4] = (_Float16)b4.x; t.v[5] = (_Float16)b4.y;
            t.v[6] = (_Float16)b4.z; t.v[7] = (_Float16)b4.w;
            w[g][c] = t;
        }
    }

    const float bhr = bhh[j], bhz = bhh[HN + j], bhn = bhh[2 * HN + j];
    unsigned long long* hb2 = (unsigned long long*)(hbuf + (size_t)R * (2 * BPR * HN));
    // u64 index i in a batch-block: j0 = 2*i (layout [wg:16][pair:24] == linear 2*i)
    const int lq  = tid / 48;                 // q-slot of j0 = 2*tid
    const int lo2 = 2 * tid - 96 * lq;        // j0 % 96
    float hprev = 0.f;

    for (int t = 0; t < TN; ++t) {
        // ---- x-gate prefetch (L1 tokens, L2 gtab); in flight during the poll
        float xr = 0.f, xz = 0.f, xn = 0.f;
        if (q < BPR) {
            const int tok = tokens[(size_t)(R * BPR + q) * TN + t];
            const float* g_ = gtab + (size_t)tok * H3N;
            xr = g_[j]; xz = g_[HN + j]; xn = g_[2 * HN + j];
        }
        // ---- batched parallel self-poll of my 4 u64 words (tag-in-data)
        {
            const unsigned long long* hin = hb2 + (t & 1) * 1536 + tid;
            const unsigned want = (unsigned)t;
            unsigned long long v0, v1, v2, v3;
            v0 = __hip_atomic_load(hin + 0 * NTH, __ATOMIC_RELAXED, __HIP_MEMORY_SCOPE_AGENT);
            v1 = __hip_atomic_load(hin + 1 * NTH, __ATOMIC_RELAXED, __HIP_MEMORY_SCOPE_AGENT);
            v2 = __hip_atomic_load(hin + 2 * NTH, __ATOMIC_RELAXED, __HIP_MEMORY_SCOPE_AGENT);
            v3 = __hip_atomic_load(hin + 3 * NTH, __ATOMIC_RELAXED, __HIP_MEMORY_SCOPE_AGENT);
            for (;;) {
                unsigned bad =
                      ((((unsigned)(v0 >> 16)) & 0xffffu) ^ want) | (((unsigned)(v0 >> 48)) ^ want)
                    | ((((unsigned)(v1 >> 16)) & 0xffffu) ^ want) | (((unsigned)(v1 >> 48)) ^ want)
                    | ((((unsigned)(v2 >> 16)) & 0xffffu) ^ want) | (((unsigned)(v2 >> 48)) ^ want)
                    | ((((unsigned)(v3 >> 16)) & 0xffffu) ^ want) | (((unsigned)(v3 >> 48)) ^ want);
                if (!bad) break;
                __builtin_amdgcn_s_sleep(1);
                v0 = __hip_atomic_load(hin + 0 * NTH, __ATOMIC_RELAXED, __HIP_MEMORY_SCOPE_AGENT);
                v1 = __hip_atomic_load(hin + 1 * NTH, __ATOMIC_RELAXED, __HIP_MEMORY_SCOPE_AGENT);
                v2 = __hip_atomic_load(hin + 2 * NTH, __ATOMIC_RELAXED, __HIP_MEMORY_SCOPE_AGENT);
                v3 = __hip_atomic_load(hin + 3 * NTH, __ATOMIC_RELAXED, __HIP_MEMORY_SCOPE_AGENT);
            }
            // deposit: u64 k covers (batch k, j0=2*tid, 2*tid+1) -> packed f16 pair
            *(unsigned*)(hlds + (0 * 8 + lq) * 112 + lo2) =
                (((unsigned)(v0 >> 32)) << 16) | ((unsigned)v0 & 0xffffu);
            *(unsigned*)(hlds + (1 * 8 + lq) * 112 + lo2) =
                (((unsigned)(v1 >> 32)) << 16) | ((unsigned)v1 & 0xffffu);
            *(unsigned*)(hlds + (2 * 8 + lq) * 112 + lo2) =
                (((unsigned)(v2 >> 32)) << 16) | ((unsigned)v2 & 0xffffu);
            *(unsigned*)(hlds + (3 * 8 + lq) * 112 + lo2) =
                (((unsigned)(v3 >> 32)) << 16) | ((unsigned)v3 & 0xffffu);
        }
        __syncthreads();                      // tile complete

        // ---- dot: c-outer, each weight register read once per step
        float ar[BPR], az[BPR], an[BPR];
#pragma unroll
        for (int b = 0; b < BPR; ++b) { ar[b] = 0.f; az[b] = 0.f; an[b] = 0.f; }
#pragma unroll
        for (int c = 0; c < 12; ++c) {
            const F16x8 w0 = w[0][c], w1 = w[1][c], w2 = w[2][c];
#pragma unroll
            for (int b = 0; b < BPR; ++b) {
                F16x8 hh; hh.v = *(const f16x8*)(hlds + (b * 8 + q) * 112 + c * 8);
#pragma unroll
                for (int p = 0; p < 4; ++p) {
                    ar[b] = fdot2(w0.p[p], hh.p[p], ar[b]);
                    az[b] = fdot2(w1.p[p], hh.p[p], az[b]);
                    an[b] = fdot2(w2.p[p], hh.p[p], an[b]);
                }
            }
        }
        // ---- reduce (DPP), gates, pack, pair via shfl, publish tagged u64
#pragma unroll
        for (int b = 0; b < BPR; ++b) {
            const float sr = octet_sum(ar[b]);
            const float sz = octet_sum(az[b]);
            const float sn = octet_sum(an[b]);
            unsigned pk = 0;
            if (q == b) {
                const float r  = 1.f / (1.f + __expf(-(xr + sr + bhr)));
                const float z  = 1.f / (1.f + __expf(-(xz + sz + bhz)));
                const float nx = xn + r * (sn + bhn);
                const float n  = 1.f - 2.f / (__expf(2.f * nx) + 1.f);   // tanh
                hprev = (1.f - z) * n + z * hprev;
                pk = ((unsigned)(t + 1) << 16)
                   | (unsigned)__builtin_bit_cast(unsigned short, (_Float16)hprev);
            }
            const unsigned pk2 = __shfl_down(pk, 8, 64);   // neighbor jl+1, same q
            if (q == b) {
                if (t < TN - 1) {
                    if (!(jl & 1))
                        __hip_atomic_store(
                            &hb2[((t + 1) & 1) * 1536 + b * 384 + wg * 24 + (jl >> 1)],
                            (unsigned long long)pk | ((unsigned long long)pk2 << 32),
                            __ATOMIC_RELAXED, __HIP_MEMORY_SCOPE_AGENT);
                } else {
                    hout[(size_t)(R * BPR + b) * HN + j] = hprev;
                }
            }
        }
        __syncthreads();   // hlds reads complete before next step's deposits
    }
}

// ---------------- K3: logits + log_softmax
__global__ void k_logits(const float* __restrict__ hfin, const float* __restrict__ wout,
                         const float* __restrict__ bout, float* __restrict__ lp) {
    const int b = blockIdx.x;
    const int o = threadIdx.x / 64;
    const int lane = threadIdx.x % 64;
    const float* hrow = hfin + (size_t)b * HN;
    const float* w = wout + (size_t)o * HN;
    float p = 0.f;
    for (int k = lane; k < HN; k += 64) p += hrow[k] * w[k];
    for (int off = 32; off > 0; off >>= 1) p += __shfl_down(p, off, 64);
    __shared__ float lg[ON];
    if (lane == 0) lg[o] = p + bout[o];
    __syncthreads();
    if (threadIdx.x == 0) {
        float m = fmaxf(lg[0], fmaxf(lg[1], lg[2]));
        float s = __expf(lg[0] - m) + __expf(lg[1] - m) + __expf(lg[2] - m);
        float ls = __logf(s);
        lp[b * ON + 0] = lg[0] - m - ls;
        lp[b * ON + 1] = lg[1] - m - ls;
        lp[b * ON + 2] = lg[2] - m - ls;
    }
}

extern "C" void kernel_launch(void* const* d_in, const int* in_sizes, int n_in,
                              void* d_out, int out_size, void* d_ws, size_t ws_size,
                              hipStream_t stream) {
    const int*   tokens = (const int*)d_in[0];
    // d_in[1] = hidden: reference zeroes it, ignored.
    const float* embed  = (const float*)d_in[2];
    const float* wih    = (const float*)d_in[3];
    const float* whh    = (const float*)d_in[4];
    const float* bih    = (const float*)d_in[5];
    const float* bhh    = (const float*)d_in[6];
    const float* wout   = (const float*)d_in[7];
    const float* bout   = (const float*)d_in[8];

    float* out = (float*)d_out;                  // [B*O logprobs][B*H h_final]
    char* ws = (char*)d_ws;
    const size_t GTAB_OFF = 0;                   // 401*2304*4 = 3,695,616
    const size_t HBUF_OFF = 3695616;             // 16*2*3072*4 = 393,216 (tagged u32)
    float*    gtab = (float*)(ws + GTAB_OFF);
    unsigned* hbuf = (unsigned*)(ws + HBUF_OFF);

    // tag protocol requires tag==0 / h==0 state on EVERY launch (graph-replayed)
    hipMemsetAsync(ws + HBUF_OFF, 0, 393216, stream);

    hipLaunchKernelGGL(k_build_gtab, dim3(H3N / 64, 16), dim3(256), 0, stream,
                       embed, wih, bih, gtab);
    hipLaunchKernelGGL(k_rnn, dim3(NREP * WGPR), dim3(NTH), 0, stream,
                       tokens, whh, gtab, bhh, hbuf, out + BN * ON);
    hipLaunchKernelGGL(k_logits, dim3(BN), dim3(192), 0, stream,
                       out + BN * ON, wout, bout, out);
}

// Round 10
// 5326.583 us; speedup vs baseline: 2.6880x; 2.6880x over previous
//
#include <hip/hip_runtime.h>

#define VOCABN 401
#define EN 256
#define HN 768
#define H3N 2304
#define ON 3
#define BN 64
#define TN 1024

// 16 replicas x 16 WGs; WG = 768 threads: 48 j's x 16 k-slices; 4 batches staged
#define NREP 16
#define WGPR 16
#define BPR  4
#define JPW  48
#define NTH  768

typedef _Float16 f16x2 __attribute__((ext_vector_type(2)));
typedef _Float16 f16x8 __attribute__((ext_vector_type(8)));
typedef unsigned long long u64;
union F16x8 { f16x8 v; f16x2 p[4]; };

__device__ __forceinline__ float fdot2(f16x2 a, f16x2 b, float c) {
#if __has_builtin(__builtin_amdgcn_fdot2)
    return __builtin_amdgcn_fdot2(a, b, c, false);
#else
    return c + (float)a[0] * (float)b[0] + (float)a[1] * (float)b[1];
#endif
}

// sum across each aligned 16-lane group; pure-VALU DPP butterfly:
// quad_perm xor1, quad_perm xor2, row_half_mirror, row_mirror.
__device__ __forceinline__ float hexsum(float x) {
    int v = __builtin_bit_cast(int, x);
    x += __builtin_bit_cast(float, __builtin_amdgcn_update_dpp(0, v, 0xB1, 0xF, 0xF, true));
    v = __builtin_bit_cast(int, x);
    x += __builtin_bit_cast(float, __builtin_amdgcn_update_dpp(0, v, 0x4E, 0xF, 0xF, true));
    v = __builtin_bit_cast(int, x);
    x += __builtin_bit_cast(float, __builtin_amdgcn_update_dpp(0, v, 0x141, 0xF, 0xF, true));
    v = __builtin_bit_cast(int, x);
    x += __builtin_bit_cast(float, __builtin_amdgcn_update_dpp(0, v, 0x140, 0xF, 0xF, true));
    return x;
}

// ---------------- K1: gtab[v][g] = dot(embed[v], W_ih[g]) + b_ih[g]  (w-stationary)
__global__ __launch_bounds__(256)
void k_build_gtab(const float* __restrict__ embed, const float* __restrict__ wih,
                  const float* __restrict__ bih, float* __restrict__ gtab) {
    const int g  = blockIdx.x * 64 + (threadIdx.x >> 2);
    const int ql = threadIdx.x & 3;
    const int v0 = blockIdx.y * 26;
    const int v1 = min(VOCABN, v0 + 26);
    float4 w[16];
    const float4* s4 = (const float4*)(wih + (size_t)g * EN + ql * 64);
#pragma unroll
    for (int i = 0; i < 16; ++i) w[i] = s4[i];
    const float bias = bih[g];
    for (int v = v0; v < v1; ++v) {
        const float4* e4 = (const float4*)(embed + (size_t)v * EN + ql * 64);
        float acc = 0.f;
#pragma unroll
        for (int i = 0; i < 16; ++i) {
            float4 e = e4[i];
            acc += w[i].x * e.x + w[i].y * e.y + w[i].z * e.z + w[i].w * e.w;
        }
        acc += __shfl_xor(acc, 1, 64);
        acc += __shfl_xor(acc, 2, 64);
        if (ql == 0) gtab[(size_t)v * H3N + g] = acc + bias;
    }
}

// ---------------- K2: persistent-weight recurrence; batch-staggered pipeline.
// Per step, 4 stages (one per batch): {verify+deposit(b) | barrier | issue poll(b+1),
// compute(b), store(b)}. A batch's data is produced 4 stages before consumption and
// its poll load is issued 1 stage early -> steady-state first-try tag hit.
// h word (u32): [31:16]=step tag, [15:0]=f16 bits; u64 = j-pair. memset-0 == t=0.
// Anti-overwrite induction identical to r9 (per batch chain). Agent-scope relaxed.
__global__ __launch_bounds__(NTH, 1)
void k_rnn(const int* __restrict__ tokens, const float* __restrict__ whh,
           const float* __restrict__ gtab, const float* __restrict__ bhh,
           unsigned* __restrict__ hbuf, float* __restrict__ hout) {
    const int R   = blockIdx.x & (NREP - 1);   // replica -> XCD R%8 (round-robin heur.)
    const int wg  = blockIdx.x >> 4;
    const int tid = threadIdx.x;
    const int jl  = tid >> 4;                  // 0..47
    const int q   = tid & 15;                  // k-slice
    const int j   = wg * JPW + jl;

    __shared__ __align__(16) _Float16 hlds[BPR * 16 * 56];  // [b][q][48+8pad] = 7168 B

    // ---- one-time: weight slice -> 18 statically-indexed f16x8 (72 VGPRs)
    F16x8 w[3][6];
#pragma unroll
    for (int g = 0; g < 3; ++g) {
        const float4* s4 = (const float4*)(whh + (size_t)(g * HN + j) * HN + q * 48);
#pragma unroll
        for (int c = 0; c < 6; ++c) {
            float4 a = s4[2 * c], b4 = s4[2 * c + 1];
            F16x8 t;
            t.v[0] = (_Float16)a.x;  t.v[1] = (_Float16)a.y;
            t.v[2] = (_Float16)a.z;  t.v[3] = (_Float16)a.w;
            t.v[4] = (_Float16)b4.x; t.v[5] = (_Float16)b4.y;
            t.v[6] = (_Float16)b4.z; t.v[7] = (_Float16)b4.w;
            w[g][c] = t;
        }
    }

    const float bhr = bhh[j], bhz = bhh[HN + j], bhn = bhh[2 * HN + j];
    u64* hb2 = (u64*)hbuf + (size_t)R * (2 * BPR * 384);
    // poller (tid<384): u64 word tid of a batch block covers j0 = 2*tid
    const int s_   = tid / 24;               // q-slot of j0
    const int off_ = (tid % 24) * 2;         // j0 % 48
    unsigned short* dep = (unsigned short*)hlds + s_ * 56 + off_;   // + b*896

    float hprev = 0.f;
    float xr = 0.f, xz = 0.f, xn = 0.f, xrn = 0.f, xzn = 0.f, xnn = 0.f;
    if (q < BPR) {                           // x-gates for t=0 (owner q handles batch q)
        const int tok = tokens[(size_t)(R * BPR + q) * TN + 0];
        const float* g_ = gtab + (size_t)tok * H3N;
        xr = g_[j]; xz = g_[HN + j]; xn = g_[2 * HN + j];
    }
    u64 v = 0, vn = 0;
    if (tid < 384)                           // prologue issue for (t=0, b=0)
        v = __hip_atomic_load(hb2 + tid, __ATOMIC_RELAXED, __HIP_MEMORY_SCOPE_AGENT);

#pragma unroll 1
    for (int t = 0; t < TN; ++t) {
#pragma unroll
        for (int b = 0; b < BPR; ++b) {
            // ---- verify (first-try hit in steady state) + deposit to tile b
            if (tid < 384) {
                const u64* cur = hb2 + ((t & 1) * BPR + b) * 384 + tid;
                const unsigned want = (unsigned)t;
                while (((((unsigned)(v >> 16)) & 0xffffu) != want) |
                       (((unsigned)(v >> 48)) != want)) {
                    __builtin_amdgcn_s_sleep(1);
                    v = __hip_atomic_load(cur, __ATOMIC_RELAXED, __HIP_MEMORY_SCOPE_AGENT);
                }
                *(unsigned*)(dep + b * 896) =
                    (((unsigned)(v >> 32)) << 16) | ((unsigned)v & 0xffffu);
            }
            __syncthreads();                 // tile b complete (barrier drains vmcnt)

            // ---- issue next stage's poll load (1 stage of compute hides latency)
            if (tid < 384 && !(t == TN - 1 && b == BPR - 1)) {
                const int nb  = (b + 1) & 3;
                const int ntp = (b == 3) ? (t + 1) : t;
                vn = __hip_atomic_load(hb2 + ((ntp & 1) * BPR + nb) * 384 + tid,
                                       __ATOMIC_RELAXED, __HIP_MEMORY_SCOPE_AGENT);
            }
            // ---- prefetch next step's x-gates during stage 0
            if (b == 0 && q < BPR && t < TN - 1) {
                const int tok = tokens[(size_t)(R * BPR + q) * TN + (t + 1)];
                const float* g_ = gtab + (size_t)tok * H3N;
                xrn = g_[j]; xzn = g_[HN + j]; xnn = g_[2 * HN + j];
            }

            // ---- compute batch b: 72 fdot2 from VGPR weights
            float ar = 0.f, az = 0.f, an = 0.f;
            const f16x8* hp = (const f16x8*)(hlds + b * 896 + q * 56);
#pragma unroll
            for (int c = 0; c < 6; ++c) {
                F16x8 hh; hh.v = hp[c];
#pragma unroll
                for (int p = 0; p < 4; ++p) {
                    ar = fdot2(w[0][c].p[p], hh.p[p], ar);
                    az = fdot2(w[1][c].p[p], hh.p[p], az);
                    an = fdot2(w[2][c].p[p], hh.p[p], an);
                }
            }
            const float sr = hexsum(ar), sz = hexsum(az), sn = hexsum(an);

            unsigned pk = 0;
            if (q == b) {                    // owner lane updates h[j] of batch b
                const float r  = 1.f / (1.f + __expf(-(xr + sr + bhr)));
                const float z  = 1.f / (1.f + __expf(-(xz + sz + bhz)));
                const float nx = xn + r * (sn + bhn);
                const float n  = 1.f - 2.f / (__expf(2.f * nx) + 1.f);   // tanh
                hprev = (1.f - z) * n + z * hprev;
                pk = ((unsigned)(t + 1) << 16)
                   | (unsigned)__builtin_bit_cast(unsigned short, (_Float16)hprev);
            }
            const unsigned pk2 = __shfl_down(pk, 16, 64);   // pair jl with jl+1
            if (q == b) {
                if (t < TN - 1) {
                    if (!(jl & 1))
                        __hip_atomic_store(
                            hb2 + (((t + 1) & 1) * BPR + b) * 384 + wg * 24 + (jl >> 1),
                            (u64)pk | ((u64)pk2 << 32),
                            __ATOMIC_RELAXED, __HIP_MEMORY_SCOPE_AGENT);
                } else {
                    hout[(size_t)(R * BPR + b) * HN + j] = hprev;
                }
            }
            v = vn;
        }
        xr = xrn; xz = xzn; xn = xnn;
    }
}

// ---------------- K3: logits + log_softmax
__global__ void k_logits(const float* __restrict__ hfin, const float* __restrict__ wout,
                         const float* __restrict__ bout, float* __restrict__ lp) {
    const int b = blockIdx.x;
    const int o = threadIdx.x / 64;
    const int lane = threadIdx.x % 64;
    const float* hrow = hfin + (size_t)b * HN;
    const float* w = wout + (size_t)o * HN;
    float p = 0.f;
    for (int k = lane; k < HN; k += 64) p += hrow[k] * w[k];
    for (int off = 32; off > 0; off >>= 1) p += __shfl_down(p, off, 64);
    __shared__ float lg[ON];
    if (lane == 0) lg[o] = p + bout[o];
    __syncthreads();
    if (threadIdx.x == 0) {
        float m = fmaxf(lg[0], fmaxf(lg[1], lg[2]));
        float s = __expf(lg[0] - m) + __expf(lg[1] - m) + __expf(lg[2] - m);
        float ls = __logf(s);
        lp[b * ON + 0] = lg[0] - m - ls;
        lp[b * ON + 1] = lg[1] - m - ls;
        lp[b * ON + 2] = lg[2] - m - ls;
    }
}

extern "C" void kernel_launch(void* const* d_in, const int* in_sizes, int n_in,
                              void* d_out, int out_size, void* d_ws, size_t ws_size,
                              hipStream_t stream) {
    const int*   tokens = (const int*)d_in[0];
    // d_in[1] = hidden: reference zeroes it, ignored.
    const float* embed  = (const float*)d_in[2];
    const float* wih    = (const float*)d_in[3];
    const float* whh    = (const float*)d_in[4];
    const float* bih    = (const float*)d_in[5];
    const float* bhh    = (const float*)d_in[6];
    const float* wout   = (const float*)d_in[7];
    const float* bout   = (const float*)d_in[8];

    float* out = (float*)d_out;                  // [B*O logprobs][B*H h_final]
    char* ws = (char*)d_ws;
    const size_t GTAB_OFF = 0;                   // 401*2304*4 = 3,695,616
    const size_t HBUF_OFF = 3695616;             // 16*2*4*384*8 = 393,216 (tagged u64)
    float*    gtab = (float*)(ws + GTAB_OFF);
    unsigned* hbuf = (unsigned*)(ws + HBUF_OFF);

    // tag protocol requires tag==0 / h==0 state on EVERY launch (graph-replayed)
    hipMemsetAsync(ws + HBUF_OFF, 0, 393216, stream);

    hipLaunchKernelGGL(k_build_gtab, dim3(H3N / 64, 16), dim3(256), 0, stream,
                       embed, wih, bih, gtab);
    hipLaunchKernelGGL(k_rnn, dim3(NREP * WGPR), dim3(NTH), 0, stream,
                       tokens, whh, gtab, bhh, hbuf, out + BN * ON);
    hipLaunchKernelGGL(k_logits, dim3(BN), dim3(192), 0, stream,
                       out + BN * ON, wout, bout, out);
}